// Round 1
// baseline (182.580 us; speedup 1.0000x reference)
//
#include <hip/hip_runtime.h>
#include <hip/hip_bf16.h>

// out[b,a,x,y] = -C0 * sum_{s,r} s[b,s,x,y] * L[s,r,a] * Fn[b,r,x,y]
// Fn = periodic 4-neighbor sum of s over the (x,y) lattice.
// Shapes: s (32,3,512,512) f32, t scalar (unused), C0 scalar, L (3,3,3) f32.

constexpr int B = 32, X = 512, Y = 512;
constexpr int XY = X * Y;

__global__ __launch_bounds__(256)
void psi0_kernel(const float* __restrict__ s,
                 const float* __restrict__ C0p,
                 const float* __restrict__ Lp,
                 float* __restrict__ out)
{
    __shared__ float Ls[27];
    if (threadIdx.x < 27) Ls[threadIdx.x] = Lp[threadIdx.x];
    __syncthreads();

    const int tid = threadIdx.x;
    const int ty  = tid & 127;           // 128 threads cover one x-row (512 / 4)
    const int row = tid >> 7;            // 2 rows per block
    const int bid = blockIdx.x;
    const int b   = bid >> 8;            // X/2 = 256 row-pairs per batch
    const int x   = ((bid & 255) << 1) + row;
    const int y0  = ty << 2;

    const int xm = (x == 0)     ? X - 1 : x - 1;
    const int xp = (x == X - 1) ? 0     : x + 1;
    const int ym = (y0 == 0)    ? Y - 1 : y0 - 1;   // wrap for left edge of float4
    const int yp = (y0 + 4 == Y) ? 0    : y0 + 4;   // wrap for right edge

    const float C0 = C0p[0];
    const size_t baseB = (size_t)b * 3 * XY;

    float4 sc[3];
    float4 Fn[3];

    #pragma unroll
    for (int c = 0; c < 3; ++c) {
        const float* p = s + baseB + (size_t)c * XY;
        const float4 ce = *(const float4*)(p + (size_t)x  * Y + y0);
        const float4 up = *(const float4*)(p + (size_t)xm * Y + y0);
        const float4 dn = *(const float4*)(p + (size_t)xp * Y + y0);
        const float  lf = p[(size_t)x * Y + ym];
        const float  rt = p[(size_t)x * Y + yp];
        sc[c] = ce;
        Fn[c].x = up.x + dn.x + lf   + ce.y;
        Fn[c].y = up.y + dn.y + ce.x + ce.z;
        Fn[c].z = up.z + dn.z + ce.y + ce.w;
        Fn[c].w = up.w + dn.w + ce.z + rt;
    }

    #pragma unroll
    for (int a = 0; a < 3; ++a) {
        float4 acc = make_float4(0.f, 0.f, 0.f, 0.f);
        #pragma unroll
        for (int ss = 0; ss < 3; ++ss) {
            #pragma unroll
            for (int r = 0; r < 3; ++r) {
                const float w = Ls[ss * 9 + r * 3 + a];
                acc.x += w * sc[ss].x * Fn[r].x;
                acc.y += w * sc[ss].y * Fn[r].y;
                acc.z += w * sc[ss].z * Fn[r].z;
                acc.w += w * sc[ss].w * Fn[r].w;
            }
        }
        float4 o;
        o.x = -C0 * acc.x;
        o.y = -C0 * acc.y;
        o.z = -C0 * acc.z;
        o.w = -C0 * acc.w;
        *(float4*)(out + baseB + (size_t)a * XY + (size_t)x * Y + y0) = o;
    }
}

extern "C" void kernel_launch(void* const* d_in, const int* in_sizes, int n_in,
                              void* d_out, int out_size, void* d_ws, size_t ws_size,
                              hipStream_t stream)
{
    const float* s   = (const float*)d_in[0];
    // d_in[1] = t (unused: coeff is t-independent with a single cc entry)
    const float* C0p = (const float*)d_in[2];
    const float* Lp  = (const float*)d_in[3];
    float* out = (float*)d_out;

    const int blocks = B * (X / 2);   // 8192 blocks, 256 threads = 2 x-rows each
    psi0_kernel<<<blocks, 256, 0, stream>>>(s, C0p, Lp, out);
}